// Round 11
// baseline (580.867 us; speedup 1.0000x reference)
//
#include <hip/hip_runtime.h>
#include <hip/hip_bf16.h>
#include <cstdint>
#include <cstddef>

typedef __bf16 bf16_t;
typedef __attribute__((ext_vector_type(8))) __bf16 bf16x8;
typedef __attribute__((ext_vector_type(4))) __bf16 bf16x4;
typedef __attribute__((ext_vector_type(4))) float f32x4;
typedef __attribute__((ext_vector_type(4))) int int4v;
typedef __attribute__((ext_vector_type(2))) unsigned uintx2;

#define DEV static __device__ __forceinline__

#define BATCH 32
#define SEQ 577
#define DMODEL 768
#define MROWS (BATCH * SEQ)   // 18464
#define MPAD 18688            // 146 * 128
#define NH 12
#define HDIM 32
#define EDIM 64
#define MLPD 3072
#define NPAD 640
#define QKVSTR 2304

DEV f32x4 mfma16(bf16x8 a, bf16x8 b, f32x4 c) {
    return __builtin_amdgcn_mfma_f32_16x16x32_bf16(a, b, c, 0, 0, 0);
}

DEV void gload16(const void* g, void* l) {
    __builtin_amdgcn_global_load_lds(
        (const __attribute__((address_space(1))) void*)(uintptr_t)g,
        (__attribute__((address_space(3))) void*)(uintptr_t)l,
        16, 0, 0);
}

DEV unsigned cvt_pk_bf16(float lo, float hi) {
    unsigned r;
    asm("v_cvt_pk_bf16_f32 %0, %1, %2" : "=v"(r) : "v"(lo), "v"(hi));
    return r;
}
DEV void plane16_swap(unsigned& a, unsigned& b) {
    asm("v_permlane16_swap_b32 %0, %1" : "+v"(a), "+v"(b));
}
DEV void plane32_swap(unsigned& a, unsigned& b) {
    asm("v_permlane32_swap_b32 %0, %1" : "+v"(a), "+v"(b));
}

// ---- bijective XCD chunking (m204) ----
DEV int xcd_swz(int orig, int nwg) {
    const int q = nwg >> 3, r = nwg & 7;
    const int xcd = orig & 7, loc = orig >> 3;
    return (xcd < r ? xcd * (q + 1) : r * (q + 1) + (xcd - r) * q) + loc;
}

// ---------------- weight fp32 -> bf16 conversion ----------------
__global__ __launch_bounds__(256)
void wconv_kernel(const float* __restrict__ wq, const float* __restrict__ wk,
                  const float* __restrict__ wv, const float* __restrict__ wo,
                  const float* __restrict__ w1, const float* __restrict__ w2,
                  bf16_t* __restrict__ dst)
{
    const size_t idx = ((size_t)blockIdx.x * 256 + threadIdx.x) * 4;
    const float* src;
    size_t off;
    if      (idx <  589824) { src = wq; off = idx; }
    else if (idx < 1179648) { src = wk; off = idx - 589824; }
    else if (idx < 1769472) { src = wv; off = idx - 1179648; }
    else if (idx < 2359296) { src = wo; off = idx - 1769472; }
    else if (idx < 4718592) { src = w1; off = idx - 2359296; }
    else                    { src = w2; off = idx - 4718592; }
    const f32x4 v = *(const f32x4*)&src[off];
    bf16x4 o;
#pragma unroll
    for (int u = 0; u < 4; ++u) o[u] = (bf16_t)v[u];
    *(bf16x4*)&dst[idx] = o;
}

// ---------------- lambda scalar ----------------
__global__ void lam_kernel(const float* __restrict__ lq1, const float* __restrict__ lk1,
                           const float* __restrict__ lq2, const float* __restrict__ lk2,
                           float* __restrict__ lam)
{
    const int l = threadIdx.x;
    float a = 0.f, c = 0.f;
    if (l < 32) { a = lq1[l] * lk1[l]; c = lq2[l] * lk2[l]; }
#pragma unroll
    for (int m = 1; m < 32; m <<= 1) { a += __shfl_xor(a, m); c += __shfl_xor(c, m); }
    if (l == 0) *lam = expf(a) - expf(c) + 0.2f;
}

// ---------------- layernorm (f32 in, bf16 out, zero pad rows) ----------------
__global__ __launch_bounds__(256)
void ln_kernel(const float* __restrict__ src, const float* __restrict__ g,
               const float* __restrict__ bt, bf16_t* __restrict__ dst, const int Mv)
{
    const int row = blockIdx.x;
    const int t = threadIdx.x;
    if (row >= Mv) {
        for (int i = t; i < DMODEL; i += 256) dst[(size_t)row * DMODEL + i] = (bf16_t)0.f;
        return;
    }
    const float* p = src + (size_t)row * DMODEL;
    const float v0 = p[t], v1 = p[t + 256], v2 = p[t + 512];
    float s = v0 + v1 + v2, s2 = v0 * v0 + v1 * v1 + v2 * v2;
#pragma unroll
    for (int m = 1; m < 64; m <<= 1) { s += __shfl_xor(s, m); s2 += __shfl_xor(s2, m); }
    __shared__ float red[8];
    const int w = t >> 6;
    if ((t & 63) == 0) { red[w] = s; red[4 + w] = s2; }
    __syncthreads();
    s  = red[0] + red[1] + red[2] + red[3];
    s2 = red[4] + red[5] + red[6] + red[7];
    const float mu  = s * (1.f / DMODEL);
    const float var = s2 * (1.f / DMODEL) - mu * mu;
    const float rs = rsqrtf(var + 1e-5f);
    bf16_t* d = dst + (size_t)row * DMODEL;
    d[t      ] = (bf16_t)((v0 - mu) * rs * g[t      ] + bt[t      ]);
    d[t + 256] = (bf16_t)((v1 - mu) * rs * g[t + 256] + bt[t + 256]);
    d[t + 512] = (bf16_t)((v2 - mu) * rs * g[t + 512] + bt[t + 512]);
}

// ======== 128x128 BK=32 GEMM, triple-buffered, 3 blocks/CU (R11) ========
// TLP lever: 48 KiB LDS -> 3 blocks/CU, 24 waves/CU; other blocks' MFMA
// covers each block's read/stage/barrier segments (m114).
// Per K-step: {4 rdA + 2 rdB + 2 gloads(kt+2); vmcnt(2); BAR; 8 MFMA; BAR}.
// Ledger (2 loads/tile): prologue VM2 = tile0 done; steady VM2 after issuing
// kt+2 = tile kt+1 done (for next step); VM0 at kt==NT-2 drains last tile.
// WAR: step kt+1 stages into buf((kt+3)%3)=buf(kt%3); step kt's reads of that
// buffer are consumed by its MFMAs before its closing BAR. Safe.
#define VM2 asm volatile("s_waitcnt vmcnt(2)" ::: "memory")
#define VM0 asm volatile("s_waitcnt vmcnt(0)" ::: "memory")
#define SB0 __builtin_amdgcn_sched_barrier(0)
#define BAR __builtin_amdgcn_s_barrier()

#define ASZ 4096   // 128*32 elems per buffer (A and B identical)

template <int EPI>
__global__ __launch_bounds__(512, 4)
void gemm3(const bf16_t* __restrict__ A, const bf16_t* __restrict__ W,
           const int K, const int N, const int NT,
           bf16_t* __restrict__ outB, float* __restrict__ outF,
           const float* __restrict__ bias, const float* __restrict__ resid,
           const int Mv)
{
    __shared__ bf16_t As[3 * ASZ];
    __shared__ bf16_t Bs[3 * ASZ];
    const int t = threadIdx.x;
    const int l = t & 63, w = t >> 6;
    const int lg = l >> 4, lc = l & 15;
    const int wr = w >> 2, wc = w & 3;          // 2 x 4 wave grid

    const int nwg = gridDim.x * gridDim.y;
    const int orig = blockIdx.y * gridDim.x + blockIdx.x;
    const int wg = xcd_swz(orig, nwg);
    const int tileRow = (wg / gridDim.y) * 128;
    const int tileCol = (wg % gridDim.y) * 128;

    // staging: 512 chunks of 16B per 128x32 tile, 1/thread.
    // LDS linear dest; source col-chunk pre-swizzled (proven 0-conflict in R9).
    const int srow = t >> 2;
    const int csrc = ((t & 3) ^ ((t >> 3) & 3)) * 8;
    const bf16_t* srcA = A + (size_t)(tileRow + srow) * K + csrc;
    const bf16_t* srcB = W + (size_t)(tileCol + srow) * K + csrc;

    f32x4 acc[4][2];
#pragma unroll
    for (int m = 0; m < 4; ++m)
#pragma unroll
        for (int n = 0; n < 2; ++n) acc[m][n] = f32x4{0.f, 0.f, 0.f, 0.f};

    // LDS read offsets (elems): row*32 + (lg ^ ((lc>>1)&3))*8
    const int rch = (lg ^ ((lc >> 1) & 3)) * 8;
    const int aoff = (wr * 64 + lc) * 32 + rch;   // + m2*512 elems (16 rows)
    const int boff = (wc * 32 + lc) * 32 + rch;   // + n2*512 elems

    bf16x8 af[4], bf[2];

    auto stageA = [&](int kt, bf16_t* dst) {
        gload16(srcA + (size_t)kt * 32, dst + t * 8);
    };
    auto stageB = [&](int kt, bf16_t* dst) {
        gload16(srcB + (size_t)kt * 32, dst + t * 8);
    };
    auto rdA = [&](const bf16_t* buf) {
#pragma unroll
        for (int m2 = 0; m2 < 4; ++m2)
            af[m2] = *(const bf16x8*)&buf[aoff + m2 * 512];
    };
    auto rdB = [&](const bf16_t* buf) {
#pragma unroll
        for (int j = 0; j < 2; ++j)
            bf[j] = *(const bf16x8*)&buf[boff + j * 512];
    };

    auto STEP = [&](int kt, const bf16_t* AsR, const bf16_t* BsR,
                    bf16_t* AsS, bf16_t* BsS) {
        rdA(AsR); rdB(BsR);
        if (kt + 2 < NT) { stageA(kt + 2, AsS); stageB(kt + 2, BsS); }
        if (kt == NT - 2) { VM0; } else if (kt < NT - 2) { VM2; }
        SB0; BAR; SB0;
        __builtin_amdgcn_s_setprio(1);
#pragma unroll
        for (int m2 = 0; m2 < 4; ++m2)
#pragma unroll
            for (int j = 0; j < 2; ++j)
                acc[m2][j] = mfma16(af[m2], bf[j], acc[m2][j]);
        __builtin_amdgcn_s_setprio(0);
        BAR;
    };

    // prologue: tiles 0 and 1, order [A, B] per tile
    stageA(0, As);        stageB(0, Bs);
    stageA(1, As + ASZ);  stageB(1, Bs + ASZ);
    VM2; BAR;

#pragma unroll 1
    for (int kt = 0; kt < NT; kt += 3) {
        STEP(kt,     As,           Bs,           As + 2 * ASZ, Bs + 2 * ASZ);
        STEP(kt + 1, As + ASZ,     Bs + ASZ,     As,           Bs);
        STEP(kt + 2, As + 2 * ASZ, Bs + 2 * ASZ, As + ASZ,     Bs + ASZ);
    }

    // C-write: per wave 64x32 at (tileRow + wr*64, tileCol + wc*32)
#pragma unroll
    for (int m = 0; m < 4; ++m) {
        const int row0 = tileRow + wr * 64 + m * 16 + 4 * lg;
#pragma unroll
        for (int n = 0; n < 2; ++n) {
            const int col = tileCol + wc * 32 + n * 16 + lc;
#pragma unroll
            for (int r = 0; r < 4; ++r) {
                const int row = row0 + r;
                float v = acc[m][n][r];
                if (EPI == 0) {
                    outB[(size_t)row * N + col] = (bf16_t)v;
                } else if (EPI == 1) {
                    const float xin = (row < Mv) ? resid[(size_t)row * N + col] : 0.f;
                    outF[(size_t)row * N + col] = v + xin;
                } else if (EPI == 2) {
                    v += bias[col];
                    v = 0.5f * v * (1.f + erff(v * 0.70710678118654752f));
                    outB[(size_t)row * N + col] = (bf16_t)v;
                } else {
                    if (row < Mv)
                        outF[(size_t)row * N + col] = v + bias[col] + resid[(size_t)row * N + col];
                }
            }
        }
    }
}

// ---------------- V transpose: qkv v-cols -> vt[(b*12+h)*64+e][n] (pad n zeroed) -----
__global__ __launch_bounds__(256)
void vtrans_kernel(const bf16_t* __restrict__ qkv, bf16_t* __restrict__ vt)
{
    const int nt = blockIdx.x, h = blockIdx.y, b = blockIdx.z;
    const int t = threadIdx.x;
    __shared__ bf16_t T[64][72];
    {
        const int nl = t >> 2, e0 = (t & 3) * 16;
        const int n = nt * 64 + nl;
        bf16x8 a, c;
        if (n < SEQ) {
            const bf16_t* src = &qkv[((size_t)b * SEQ + n) * QKVSTR + 1536 + h * EDIM + e0];
            a = *(const bf16x8*)src;
            c = *(const bf16x8*)(src + 8);
        } else {
#pragma unroll
            for (int u = 0; u < 8; ++u) { a[u] = (bf16_t)0.f; c[u] = (bf16_t)0.f; }
        }
#pragma unroll
        for (int u = 0; u < 8; ++u) { T[e0 + u][nl] = a[u]; T[e0 + 8 + u][nl] = c[u]; }
    }
    __syncthreads();
    {
        const int e = t >> 2, n0 = (t & 3) * 16;
        bf16x8 a, c;
#pragma unroll
        for (int u = 0; u < 8; ++u) { a[u] = T[e][n0 + u]; c[u] = T[e][n0 + 8 + u]; }
        bf16_t* d = &vt[((size_t)(b * NH + h) * EDIM + e) * NPAD + nt * 64 + n0];
        *(bf16x8*)d = a;
        *(bf16x8*)(d + 8) = c;
    }
}

// ---------------- differential flash attention v4 (unchanged) ----------------
__global__ __launch_bounds__(256)
void attn_kernel(const bf16_t* __restrict__ qkv, const bf16_t* __restrict__ vtp,
                 const float* __restrict__ lamp, const float* __restrict__ subg,
                 bf16_t* __restrict__ outp)
{
    const int orig = blockIdx.x + 10 * (blockIdx.y + 12 * blockIdx.z);
    const int wg = xcd_swz(orig, 3840);
    const int qt = wg % 10;
    const int h  = (wg / 10) % 12;
    const int b  = wg / 120;
    const int t = threadIdx.x, w = t >> 6, l = t & 63;
    const int lg = l >> 4, lc = l & 15;
    const float lam = *lamp;
    const float SC2 = 0.25503487f;            // (1/sqrt(32)) * log2(e)
    const float MARG = 8.0f * 0.25503487f;    // fixed shift, raw m = 8

    __shared__ bf16_t Ks[2][64 * 64];
    __shared__ bf16_t Vs[2][64 * 64];

    const size_t mb = (size_t)b * SEQ;
    const int q0row = qt * 64 + w * 16;

    bf16x8 qf[2];
#pragma unroll
    for (int hh = 0; hh < 2; ++hh)
        qf[hh] = *(const bf16x8*)&qkv[(mb + q0row + lc) * QKVSTR
                                      + h * 64 + hh * 32 + 8 * lg];

    f32x4 O[2][4];
    f32x4 Ol[2];
#pragma unroll
    for (int hh = 0; hh < 2; ++hh) {
        Ol[hh] = f32x4{0.f, 0.f, 0.f, 0.f};
#pragma unroll
        for (int ef = 0; ef < 4; ++ef) O[hh][ef] = f32x4{0.f, 0.f, 0.f, 0.f};
    }

    bf16x8 ones;
#pragma unroll
    for (int u = 0; u < 8; ++u) ones[u] = (bf16_t)1.0f;

    const int r0 = t >> 3, c0 = (t & 7);
    const int r1 = r0 + 32;
    const bf16_t* kg0 = &qkv[(mb + r0) * QKVSTR + 768 + h * 64 + ((c0 ^ (r0 & 7)) * 8)];
    const bf16_t* kg1 = &qkv[(mb + r1) * QKVSTR + 768 + h * 64 + ((c0 ^ (r1 & 7)) * 8)];
    const bf16_t* vg0 = &vtp[(size_t)((b * NH + h) * EDIM + r0) * NPAD + ((c0 ^ (r0 & 7)) * 8)];
    const bf16_t* vg1 = &vtp[(size_t)((b * NH + h) * EDIM + r1) * NPAD + ((c0 ^ (r1 & 7)) * 8)];

    auto stage = [&](int kt, int bufi) {
        gload16(kg0 + (size_t)kt * (64 * QKVSTR), &Ks[bufi][t * 8]);
        gload16(kg1 + (size_t)kt * (64 * QKVSTR), &Ks[bufi][(t + 256) * 8]);
        gload16(vg0 + kt * 64, &Vs[bufi][t * 8]);
        gload16(vg1 + kt * 64, &Vs[bufi][(t + 256) * 8]);
    };

    stage(0, 0);
    int buf = 0;

    const int swz = lc & 7;
    int koff[2], voff[2];
#pragma unroll
    for (int hh = 0; hh < 2; ++hh) koff[hh] = lc * 64 + (((hh * 4 + lg) ^ swz) * 8);
#pragma unroll
    for (int ks = 0; ks < 2; ++ks) voff[ks] = lc * 64 + (((ks * 4 + lg) ^ swz) * 8);

#pragma unroll 1
    for (int kt = 0; kt < 10; ++kt) {
        __builtin_amdgcn_s_barrier();
        if (kt < 9) {
            stage(kt + 1, buf ^ 1);
            asm volatile("s_waitcnt vmcnt(4)" ::: "memory");
        } else {
            VM0;
        }
        __builtin_amdgcn_s_barrier();
        __builtin_amdgcn_sched_barrier(0);

        const bf16_t* Kb = &Ks[buf][0];
        const bf16_t* Vb = &Vs[buf][0];

#pragma unroll
        for (int hh = 0; hh < 2; ++hh) {
            bf16x8 kf[4];
#pragma unroll
            for (int f = 0; f < 4; ++f)
                kf[f] = *(const bf16x8*)&Kb[koff[hh] + f * 1024];
            f32x4 s[4];
#pragma unroll
            for (int f = 0; f < 4; ++f)
                s[f] = mfma16(kf[f], qf[hh], f32x4{0.f, 0.f, 0.f, 0.f});
            if (kt == 9) {
#pragma unroll
                for (int f = 0; f < 4; ++f)
#pragma unroll
                    for (int r = 0; r < 4; ++r)
                        if (f | r) s[f][r] = -3e38f;
                if (lg != 0) s[0][0] = -3e38f;
            }
            unsigned wd[4][2];
#pragma unroll
            for (int f = 0; f < 4; ++f) {
                float p0 = __builtin_amdgcn_exp2f(__builtin_fmaf(s[f][0], SC2, -MARG));
                float p1 = __builtin_amdgcn_exp2f(__builtin_fmaf(s[f][1], SC2, -MARG));
                float p2 = __builtin_amdgcn_exp2f(__builtin_fmaf(s[f][2], SC2, -MARG));
                float p3 = __builtin_amdgcn_exp2f(__builtin_fmaf(s[f][3], SC2, -MARG));
                wd[f][0] = cvt_pk_bf16(p0, p1);
                wd[f][1] = cvt_pk_bf16(p2, p3);
            }
#pragma unroll
            for (int half = 0; half < 2; ++half) {
#pragma unroll
                for (int p = 0; p < 2; ++p) {
                    unsigned& Aa = wd[half * 2][p];
                    unsigned& Bb = wd[half * 2 + 1][p];
                    plane32_swap(Aa, Bb);
                    plane16_swap(Aa, Bb);
                }
            }
            const bf16x8 pa0 = __builtin_bit_cast(bf16x8,
                int4v{(int)wd[0][0], (int)wd[0][1], (int)wd[1][0], (int)wd[1][1]});
            const bf16x8 pa1 = __builtin_bit_cast(bf16x8,
                int4v{(int)wd[2][0], (int)wd[2][1], (int)wd[3][0], (int)wd[3][1]});

#pragma unroll
            for (int ef = 0; ef < 4; ++ef) {
                const bf16x8 vb0 = *(const bf16x8*)&Vb[voff[0] + ef * 1024];
                const bf16x8 vb1 = *(const bf16x8*)&Vb[voff[1] + ef * 1024];
                O[hh][ef] = mfma16(vb0, pa0, O[hh][ef]);
                O[hh][ef] = mfma16(vb1, pa1, O[hh][ef]);
            }
            Ol[hh] = mfma16(ones, pa0, Ol[hh]);
            Ol[hh] = mfma16(ones, pa1, Ol[hh]);
        }
        buf ^= 1;
    }

    {
        const float i0 = 1.f / Ol[0][0];
        const float i1 = lam / Ol[1][0];
        float comb[4][4];
        float ms = 0.f;
#pragma unroll
        for (int ef = 0; ef < 4; ++ef)
#pragma unroll
            for (int r = 0; r < 4; ++r) {
                const float o = O[0][ef][r] * i0 - O[1][ef][r] * i1;
                comb[ef][r] = o;
                ms += o * o;
            }
        ms += __shfl_xor(ms, 16);
        ms += __shfl_xor(ms, 32);
        const float sc = rsqrtf(ms * (1.f / 64.f) + 1e-5f) * 0.8f;
        const int nq = q0row + lc;
        if (nq < SEQ) {
            bf16_t* dst = &outp[(mb + nq) * DMODEL + h * EDIM + 4 * lg];
#pragma unroll
            for (int ef = 0; ef < 4; ++ef) {
                const f32x4 g4 = *(const f32x4*)&subg[ef * 16 + 4 * lg];
                const unsigned u0 = cvt_pk_bf16(comb[ef][0] * sc * g4[0],
                                                comb[ef][1] * sc * g4[1]);
                const unsigned u1 = cvt_pk_bf16(comb[ef][2] * sc * g4[2],
                                                comb[ef][3] * sc * g4[3]);
                *(uintx2*)(dst + ef * 16) = uintx2{u0, u1};
            }
        }
    }
}

// ---------------- launch ----------------
extern "C" void kernel_launch(void* const* d_in, const int* in_sizes, int n_in,
                              void* d_out, int out_size, void* d_ws, size_t ws_size,
                              hipStream_t stream)
{
    const float* x    = (const float*)d_in[0];
    const float* ln1g = (const float*)d_in[1];
    const float* ln1b = (const float*)d_in[2];
    const float* wq   = (const float*)d_in[3];
    const float* wk   = (const float*)d_in[4];
    const float* wv   = (const float*)d_in[5];
    const float* wo   = (const float*)d_in[6];
    const float* lq1  = (const float*)d_in[7];
    const float* lk1  = (const float*)d_in[8];
    const float* lq2  = (const float*)d_in[9];
    const float* lk2  = (const float*)d_in[10];
    const float* subg = (const float*)d_in[11];
    const float* ln2g = (const float*)d_in[12];
    const float* ln2b = (const float*)d_in[13];
    const float* w1   = (const float*)d_in[14];
    const float* b1   = (const float*)d_in[15];
    const float* w2   = (const float*)d_in[16];
    const float* b2   = (const float*)d_in[17];

    char* ws = (char*)d_ws;
    bf16_t* wAll = (bf16_t*)ws;               // wq|wk|wv (fused) | wo | w1 | w2
    bf16_t* wob = wAll + 1769472;
    bf16_t* w1b = wAll + 2359296;
    bf16_t* w2b = wAll + 4718592;
    ws += 7077888ull * 2;
    float* lamP = (float*)ws; ws += 256;
    bf16_t* xn   = (bf16_t*)ws; ws += (size_t)MPAD * DMODEL * 2;
    bf16_t* qkvb = (bf16_t*)ws;               // [MPAD][2304]; h1 aliases here later
    bf16_t* h1   = qkvb;
    ws += (size_t)MPAD * QKVSTR * 2;
    bf16_t* vtb  = (bf16_t*)ws; ws += (size_t)(BATCH * NH) * EDIM * NPAD * 2;
    bf16_t* aout = (bf16_t*)ws; ws += (size_t)MPAD * DMODEL * 2;
    float* x1    = (float*)ws;  ws += (size_t)MPAD * DMODEL * 4;

    wconv_kernel<<<6912, 256, 0, stream>>>(wq, wk, wv, wo, w1, w2, wAll);
    lam_kernel<<<1, 64, 0, stream>>>(lq1, lk1, lq2, lk2, lamP);
    ln_kernel<<<MPAD, 256, 0, stream>>>(x, ln1g, ln1b, xn, MROWS);

    // fused QKV: [MPAD][768] x [2304][768]^T
    gemm3<0><<<dim3(146, 18), 512, 0, stream>>>(xn, wAll, 768, QKVSTR, 24,
                                                qkvb, nullptr, nullptr, nullptr, MROWS);

    vtrans_kernel<<<dim3(10, 12, 32), 256, 0, stream>>>(qkvb, vtb);
    attn_kernel<<<dim3(10, 12, 32), 256, 0, stream>>>(qkvb, vtb, lamP, subg, aout);

    gemm3<1><<<dim3(146, 6), 512, 0, stream>>>(aout, wob, 768, 768, 24,
                                               nullptr, x1, nullptr, x, MROWS);
    ln_kernel<<<MPAD, 256, 0, stream>>>(x1, ln2g, ln2b, xn, MROWS);
    gemm3<2><<<dim3(146, 24), 512, 0, stream>>>(xn, w1b, 768, MLPD, 24,
                                                h1, nullptr, b1, nullptr, MROWS);
    gemm3<3><<<dim3(146, 6), 512, 0, stream>>>(h1, w2b, MLPD, 768, 96,
                                               nullptr, (float*)d_out, b2, x1, MROWS);
}

// Round 12
// 541.837 us; speedup vs baseline: 1.0720x; 1.0720x over previous
//
#include <hip/hip_runtime.h>
#include <hip/hip_bf16.h>
#include <cstdint>
#include <cstddef>

typedef __bf16 bf16_t;
typedef __attribute__((ext_vector_type(8))) __bf16 bf16x8;
typedef __attribute__((ext_vector_type(4))) __bf16 bf16x4;
typedef __attribute__((ext_vector_type(4))) float f32x4;
typedef __attribute__((ext_vector_type(4))) int int4v;
typedef __attribute__((ext_vector_type(2))) unsigned uintx2;

#define DEV static __device__ __forceinline__

#define BATCH 32
#define SEQ 577
#define DMODEL 768
#define MROWS (BATCH * SEQ)   // 18464
#define MPAD 18688            // 146 * 128
#define NH 12
#define HDIM 32
#define EDIM 64
#define MLPD 3072
#define NPAD 640
#define QKVSTR 2304

DEV f32x4 mfma16(bf16x8 a, bf16x8 b, f32x4 c) {
    return __builtin_amdgcn_mfma_f32_16x16x32_bf16(a, b, c, 0, 0, 0);
}

DEV void gload16(const void* g, void* l) {
    __builtin_amdgcn_global_load_lds(
        (const __attribute__((address_space(1))) void*)(uintptr_t)g,
        (__attribute__((address_space(3))) void*)(uintptr_t)l,
        16, 0, 0);
}

DEV unsigned cvt_pk_bf16(float lo, float hi) {
    unsigned r;
    asm("v_cvt_pk_bf16_f32 %0, %1, %2" : "=v"(r) : "v"(lo), "v"(hi));
    return r;
}
DEV void plane16_swap(unsigned& a, unsigned& b) {
    asm("v_permlane16_swap_b32 %0, %1" : "+v"(a), "+v"(b));
}
DEV void plane32_swap(unsigned& a, unsigned& b) {
    asm("v_permlane32_swap_b32 %0, %1" : "+v"(a), "+v"(b));
}

// ---- bijective XCD chunking (m204) ----
DEV int xcd_swz(int orig, int nwg) {
    const int q = nwg >> 3, r = nwg & 7;
    const int xcd = orig & 7, loc = orig >> 3;
    return (xcd < r ? xcd * (q + 1) : r * (q + 1) + (xcd - r) * q) + loc;
}

// ---------------- weight fp32 -> bf16 conversion ----------------
__global__ __launch_bounds__(256)
void wconv_kernel(const float* __restrict__ wq, const float* __restrict__ wk,
                  const float* __restrict__ wv, const float* __restrict__ wo,
                  const float* __restrict__ w1, const float* __restrict__ w2,
                  bf16_t* __restrict__ dst)
{
    const size_t idx = ((size_t)blockIdx.x * 256 + threadIdx.x) * 4;
    const float* src;
    size_t off;
    if      (idx <  589824) { src = wq; off = idx; }
    else if (idx < 1179648) { src = wk; off = idx - 589824; }
    else if (idx < 1769472) { src = wv; off = idx - 1179648; }
    else if (idx < 2359296) { src = wo; off = idx - 1769472; }
    else if (idx < 4718592) { src = w1; off = idx - 2359296; }
    else                    { src = w2; off = idx - 4718592; }
    const f32x4 v = *(const f32x4*)&src[off];
    bf16x4 o;
#pragma unroll
    for (int u = 0; u < 4; ++u) o[u] = (bf16_t)v[u];
    *(bf16x4*)&dst[idx] = o;
}

// ---------------- lambda scalar ----------------
__global__ void lam_kernel(const float* __restrict__ lq1, const float* __restrict__ lk1,
                           const float* __restrict__ lq2, const float* __restrict__ lk2,
                           float* __restrict__ lam)
{
    const int l = threadIdx.x;
    float a = 0.f, c = 0.f;
    if (l < 32) { a = lq1[l] * lk1[l]; c = lq2[l] * lk2[l]; }
#pragma unroll
    for (int m = 1; m < 32; m <<= 1) { a += __shfl_xor(a, m); c += __shfl_xor(c, m); }
    if (l == 0) *lam = expf(a) - expf(c) + 0.2f;
}

// ---------------- layernorm (f32 in, bf16 out, zero pad rows) ----------------
__global__ __launch_bounds__(256)
void ln_kernel(const float* __restrict__ src, const float* __restrict__ g,
               const float* __restrict__ bt, bf16_t* __restrict__ dst, const int Mv)
{
    const int row = blockIdx.x;
    const int t = threadIdx.x;
    if (row >= Mv) {
        for (int i = t; i < DMODEL; i += 256) dst[(size_t)row * DMODEL + i] = (bf16_t)0.f;
        return;
    }
    const float* p = src + (size_t)row * DMODEL;
    const float v0 = p[t], v1 = p[t + 256], v2 = p[t + 512];
    float s = v0 + v1 + v2, s2 = v0 * v0 + v1 * v1 + v2 * v2;
#pragma unroll
    for (int m = 1; m < 64; m <<= 1) { s += __shfl_xor(s, m); s2 += __shfl_xor(s2, m); }
    __shared__ float red[8];
    const int w = t >> 6;
    if ((t & 63) == 0) { red[w] = s; red[4 + w] = s2; }
    __syncthreads();
    s  = red[0] + red[1] + red[2] + red[3];
    s2 = red[4] + red[5] + red[6] + red[7];
    const float mu  = s * (1.f / DMODEL);
    const float var = s2 * (1.f / DMODEL) - mu * mu;
    const float rs = rsqrtf(var + 1e-5f);
    bf16_t* d = dst + (size_t)row * DMODEL;
    d[t      ] = (bf16_t)((v0 - mu) * rs * g[t      ] + bt[t      ]);
    d[t + 256] = (bf16_t)((v1 - mu) * rs * g[t + 256] + bt[t + 256]);
    d[t + 512] = (bf16_t)((v2 - mu) * rs * g[t + 512] + bt[t + 512]);
}

// ======== 128x256 BK=32 GEMM, triple-buffered, 2 blocks/CU (R9 verbatim) ========
// Best measured GEMM structure (R9: 559 us total, MfmaUtil 29%, 0 conflicts).
// Per K-step: P0 {rdA x4 + rdB01 x2; stage A@kt+2; BAR; 8 MFMA; BAR}
//             P1 {rdB23 x2; stage B@kt+2 x2; vmcnt(3); BAR; 8 MFMA; BAR}
#define VM3 asm volatile("s_waitcnt vmcnt(3)" ::: "memory")
#define VM2 asm volatile("s_waitcnt vmcnt(2)" ::: "memory")
#define VM0 asm volatile("s_waitcnt vmcnt(0)" ::: "memory")
#define SB0 __builtin_amdgcn_sched_barrier(0)
#define BAR __builtin_amdgcn_s_barrier()

#define ASZ 4096   // 128*32 elems per A buffer
#define BSZ 8192   // 256*32 elems per B buffer

#define QUAD8(H, BP)                                                         \
    do {                                                                     \
        __builtin_amdgcn_s_setprio(1);                                       \
        _Pragma("unroll")                                                    \
        for (int m2_ = 0; m2_ < 4; ++m2_)                                    \
            _Pragma("unroll")                                                \
            for (int j_ = 0; j_ < 2; ++j_)                                   \
                acc[m2_][(H) * 2 + j_] =                                     \
                    mfma16(af[m2_], BP[j_], acc[m2_][(H) * 2 + j_]);         \
        __builtin_amdgcn_s_setprio(0);                                       \
    } while (0)

template <int EPI>
__global__ __launch_bounds__(512, 4)
void gemm4(const bf16_t* __restrict__ A, const bf16_t* __restrict__ W,
           const int K, const int N, const int NT,
           bf16_t* __restrict__ outB, float* __restrict__ outF,
           const float* __restrict__ bias, const float* __restrict__ resid,
           const int Mv)
{
    __shared__ bf16_t As[3 * ASZ];
    __shared__ bf16_t Bs[3 * BSZ];
    const int t = threadIdx.x;
    const int l = t & 63, w = t >> 6;
    const int lg = l >> 4, lc = l & 15;
    const int wr = w >> 2, wc = w & 3;          // 2 x 4 wave grid

    const int nwg = gridDim.x * gridDim.y;
    const int orig = blockIdx.y * gridDim.x + blockIdx.x;
    const int wg = xcd_swz(orig, nwg);
    const int tileRow = (wg / gridDim.y) * 128;
    const int tileCol = (wg % gridDim.y) * 256;

    const int srow = t >> 2;
    const int csrc = ((t & 3) ^ ((t >> 3) & 3)) * 8;
    const bf16_t* srcA  = A + (size_t)(tileRow + srow) * K + csrc;
    const bf16_t* srcB0 = W + (size_t)(tileCol + srow) * K + csrc;
    const bf16_t* srcB1 = W + (size_t)(tileCol + 128 + srow) * K + csrc;

    f32x4 acc[4][4];
#pragma unroll
    for (int m = 0; m < 4; ++m)
#pragma unroll
        for (int n = 0; n < 4; ++n) acc[m][n] = f32x4{0.f, 0.f, 0.f, 0.f};

    const int rch = (lg ^ ((lc >> 1) & 3)) * 8;
    const int aoff = (wr * 64 + lc) * 32 + rch;
    const int boff = (wc * 64 + lc) * 32 + rch;

    bf16x8 af[4], b01[2], b23[2];

    auto stageA = [&](int kt, bf16_t* dst) {
        gload16(srcA + (size_t)kt * 32, dst + t * 8);
    };
    auto stageB = [&](int kt, bf16_t* dst) {
        gload16(srcB0 + (size_t)kt * 32, dst + t * 8);
        gload16(srcB1 + (size_t)kt * 32, dst + (t + 512) * 8);
    };
    auto rdA = [&](const bf16_t* buf) {
#pragma unroll
        for (int m2 = 0; m2 < 4; ++m2)
            af[m2] = *(const bf16x8*)&buf[aoff + m2 * 512];
    };
    auto rdB = [&](const bf16_t* buf, int h, bf16x8* bp) {
#pragma unroll
        for (int j = 0; j < 2; ++j)
            bp[j] = *(const bf16x8*)&buf[boff + (h * 2 + j) * 512];
    };

    auto STEP = [&](int kt, const bf16_t* AsR, const bf16_t* BsR,
                    bf16_t* AsS, bf16_t* BsS) {
        // P0
        rdA(AsR); rdB(BsR, 0, b01);
        if (kt + 2 < NT) stageA(kt + 2, AsS);
        SB0; BAR; SB0;
        QUAD8(0, b01);
        BAR;
        // P1
        rdB(BsR, 1, b23);
        if (kt + 2 < NT) stageB(kt + 2, BsS);
        if (kt == NT - 2) { VM0; } else if (kt < NT - 2) { VM3; }
        SB0; BAR; SB0;
        QUAD8(1, b23);
        BAR;
    };

    stageA(0, As);          stageB(0, Bs);
    stageA(1, As + ASZ);    stageB(1, Bs + BSZ);
    VM3; BAR;

#pragma unroll 1
    for (int kt = 0; kt < NT; kt += 3) {
        STEP(kt,     As,           Bs,           As + 2 * ASZ, Bs + 2 * BSZ);
        STEP(kt + 1, As + ASZ,     Bs + BSZ,     As,           Bs);
        STEP(kt + 2, As + 2 * ASZ, Bs + 2 * BSZ, As + ASZ,     Bs + BSZ);
    }

#pragma unroll
    for (int m = 0; m < 4; ++m) {
        const int row0 = tileRow + wr * 64 + m * 16 + 4 * lg;
#pragma unroll
        for (int n = 0; n < 4; ++n) {
            const int col = tileCol + wc * 64 + n * 16 + lc;
#pragma unroll
            for (int r = 0; r < 4; ++r) {
                const int row = row0 + r;
                float v = acc[m][n][r];
                if (EPI == 0) {
                    outB[(size_t)row * N + col] = (bf16_t)v;
                } else if (EPI == 1) {
                    const float xin = (row < Mv) ? resid[(size_t)row * N + col] : 0.f;
                    outF[(size_t)row * N + col] = v + xin;
                } else if (EPI == 2) {
                    v += bias[col];
                    v = 0.5f * v * (1.f + erff(v * 0.70710678118654752f));
                    outB[(size_t)row * N + col] = (bf16_t)v;
                } else {
                    if (row < Mv)
                        outF[(size_t)row * N + col] = v + bias[col] + resid[(size_t)row * N + col];
                }
            }
        }
    }
}

// ---------------- V transpose: qkv v-cols -> vt[(b*12+h)*64+e][n] (pad n zeroed) -----
__global__ __launch_bounds__(256)
void vtrans_kernel(const bf16_t* __restrict__ qkv, bf16_t* __restrict__ vt)
{
    const int nt = blockIdx.x, h = blockIdx.y, b = blockIdx.z;
    const int t = threadIdx.x;
    __shared__ bf16_t T[64][72];
    {
        const int nl = t >> 2, e0 = (t & 3) * 16;
        const int n = nt * 64 + nl;
        bf16x8 a, c;
        if (n < SEQ) {
            const bf16_t* src = &qkv[((size_t)b * SEQ + n) * QKVSTR + 1536 + h * EDIM + e0];
            a = *(const bf16x8*)src;
            c = *(const bf16x8*)(src + 8);
        } else {
#pragma unroll
            for (int u = 0; u < 8; ++u) { a[u] = (bf16_t)0.f; c[u] = (bf16_t)0.f; }
        }
#pragma unroll
        for (int u = 0; u < 8; ++u) { T[e0 + u][nl] = a[u]; T[e0 + 8 + u][nl] = c[u]; }
    }
    __syncthreads();
    {
        const int e = t >> 2, n0 = (t & 3) * 16;
        bf16x8 a, c;
#pragma unroll
        for (int u = 0; u < 8; ++u) { a[u] = T[e][n0 + u]; c[u] = T[e][n0 + 8 + u]; }
        bf16_t* d = &vt[((size_t)(b * NH + h) * EDIM + e) * NPAD + nt * 64 + n0];
        *(bf16x8*)d = a;
        *(bf16x8*)(d + 8) = c;
    }
}

// ---------------- differential flash attention v5: hh split across waves ----------
// 8 waves/block (512 thr): wave = (qsub = w>>1, hh = w&1). Per-wave serial
// chain (QK->exp2->pack->permlane->PV) covers ONE head -> half the latency
// chain and half the VGPR state of v4. Epilogue: hh=1 waves publish O,l via
// LDS scratch (reuses Ks/Vs), hh=0 waves combine + rmsnorm + store.
__global__ __launch_bounds__(512)
void attn_kernel(const bf16_t* __restrict__ qkv, const bf16_t* __restrict__ vtp,
                 const float* __restrict__ lamp, const float* __restrict__ subg,
                 bf16_t* __restrict__ outp)
{
    const int orig = blockIdx.x + 10 * (blockIdx.y + 12 * blockIdx.z);
    const int wg = xcd_swz(orig, 3840);
    const int qt = wg % 10;
    const int h  = (wg / 10) % 12;
    const int b  = wg / 120;
    const int t = threadIdx.x, w = t >> 6, l = t & 63;
    const int lg = l >> 4, lc = l & 15;
    const int qsub = w >> 1, hh = w & 1;
    const float lam = *lamp;
    const float SC2 = 0.25503487f;            // (1/sqrt(32)) * log2(e)
    const float MARG = 8.0f * 0.25503487f;    // fixed shift, raw m = 8

    __shared__ bf16_t Ks[2][64 * 64];   // 16 KB; reused as f32 O-scratch in epilogue
    __shared__ bf16_t Vs[2][64 * 64];   // 16 KB; reused as f32 l-scratch

    const size_t mb = (size_t)b * SEQ;
    const int q0row = qt * 64 + qsub * 16;

    // Q fragment (B-operand of swapped QK), own head only
    const bf16x8 qf = *(const bf16x8*)&qkv[(mb + q0row + lc) * QKVSTR
                                           + h * 64 + hh * 32 + 8 * lg];

    f32x4 O[4];
    f32x4 Ol = f32x4{0.f, 0.f, 0.f, 0.f};
#pragma unroll
    for (int ef = 0; ef < 4; ++ef) O[ef] = f32x4{0.f, 0.f, 0.f, 0.f};

    bf16x8 ones;
#pragma unroll
    for (int u = 0; u < 8; ++u) ones[u] = (bf16_t)1.0f;

    // staging: 512 thr x 2 chunks (1 K-chunk + 1 V-chunk). row = t>>3, c = t&7.
    const int r0 = t >> 3, c0 = t & 7;
    const bf16_t* kg = &qkv[(mb + r0) * QKVSTR + 768 + h * 64 + ((c0 ^ (r0 & 7)) * 8)];
    const bf16_t* vg = &vtp[(size_t)((b * NH + h) * EDIM + r0) * NPAD + ((c0 ^ (r0 & 7)) * 8)];

    auto stage = [&](int kt, int bufi) {
        gload16(kg + (size_t)kt * (64 * QKVSTR), &Ks[bufi][t * 8]);
        gload16(vg + kt * 64, &Vs[bufi][t * 8]);
    };

    stage(0, 0);
    int buf = 0;

    const int swz = lc & 7;
    const int koff = lc * 64 + (((hh * 4 + lg) ^ swz) * 8);
    int voff[2];
#pragma unroll
    for (int ks = 0; ks < 2; ++ks) voff[ks] = lc * 64 + (((ks * 4 + lg) ^ swz) * 8);

#pragma unroll 1
    for (int kt = 0; kt < 10; ++kt) {
        BAR;                               // all waves done reading buf^1
        if (kt < 9) {
            stage(kt + 1, buf ^ 1);        // 2 outstanding (kt) + 2 (kt+1)
            VM2;                           // tile kt's 2 loads landed
        } else {
            VM0;
        }
        BAR;
        SB0;

        const bf16_t* Kb = &Ks[buf][0];
        const bf16_t* Vb = &Vs[buf][0];

        // K fragments (A-operand): A[m=krow=lc][d=8lg+j], own head
        bf16x8 kf[4];
#pragma unroll
        for (int f = 0; f < 4; ++f)
            kf[f] = *(const bf16x8*)&Kb[koff + f * 1024];
        f32x4 s[4];
#pragma unroll
        for (int f = 0; f < 4; ++f)
            s[f] = mfma16(kf[f], qf, f32x4{0.f, 0.f, 0.f, 0.f});
        if (kt == 9) {
#pragma unroll
            for (int f = 0; f < 4; ++f)
#pragma unroll
                for (int r = 0; r < 4; ++r)
                    if (f | r) s[f][r] = -3e38f;
            if (lg != 0) s[0][0] = -3e38f;
        }
        unsigned wd[4][2];
#pragma unroll
        for (int f = 0; f < 4; ++f) {
            float p0 = __builtin_amdgcn_exp2f(__builtin_fmaf(s[f][0], SC2, -MARG));
            float p1 = __builtin_amdgcn_exp2f(__builtin_fmaf(s[f][1], SC2, -MARG));
            float p2 = __builtin_amdgcn_exp2f(__builtin_fmaf(s[f][2], SC2, -MARG));
            float p3 = __builtin_amdgcn_exp2f(__builtin_fmaf(s[f][3], SC2, -MARG));
            wd[f][0] = cvt_pk_bf16(p0, p1);
            wd[f][1] = cvt_pk_bf16(p2, p3);
        }
#pragma unroll
        for (int half = 0; half < 2; ++half) {
#pragma unroll
            for (int p = 0; p < 2; ++p) {
                unsigned& Aa = wd[half * 2][p];
                unsigned& Bb = wd[half * 2 + 1][p];
                plane32_swap(Aa, Bb);
                plane16_swap(Aa, Bb);
            }
        }
        const bf16x8 pa0 = __builtin_bit_cast(bf16x8,
            int4v{(int)wd[0][0], (int)wd[0][1], (int)wd[1][0], (int)wd[1][1]});
        const bf16x8 pa1 = __builtin_bit_cast(bf16x8,
            int4v{(int)wd[2][0], (int)wd[2][1], (int)wd[3][0], (int)wd[3][1]});

#pragma unroll
        for (int ef = 0; ef < 4; ++ef) {
            const bf16x8 vb0 = *(const bf16x8*)&Vb[voff[0] + ef * 1024];
            const bf16x8 vb1 = *(const bf16x8*)&Vb[voff[1] + ef * 1024];
            O[ef] = mfma16(vb0, pa0, O[ef]);
            O[ef] = mfma16(vb1, pa1, O[ef]);
        }
        Ol = mfma16(ones, pa0, Ol);
        Ol = mfma16(ones, pa1, Ol);
        buf ^= 1;
    }

    // ---- epilogue: hh=1 publishes O,l via LDS; hh=0 combines + rmsnorm ----
    float* oscr = (float*)&Ks[0][0];   // 4 qsub x 1024 f32 = 16 KB (exact fit)
    float* lscr = (float*)&Vs[0][0];   // 4 qsub x 16 f32

    BAR;   // all K/V LDS reads of the last tile complete before overwrite
    if (hh == 1) {
        float* od = oscr + qsub * 1024;
#pragma unroll
        for (int ef = 0; ef < 4; ++ef)
#pragma unroll
            for (int r = 0; r < 4; ++r)
                od[(ef * 16 + 4 * lg + r) * 16 + lc] = O[ef][r];
        lscr[qsub * 16 + lc] = Ol[0];
    }
    asm volatile("s_waitcnt lgkmcnt(0)" ::: "memory");
    BAR;
    if (hh == 0) {
        const float i0 = 1.f / Ol[0];
        const float i1 = lam / lscr[qsub * 16 + lc];
        const float* od = oscr + qsub * 1024;
        float comb[4][4];
        float ms = 0.f;
#pragma unroll
        for (int ef = 0; ef < 4; ++ef)
#pragma unroll
            for (int r = 0; r < 4; ++r) {
                const float o = O[ef][r] * i0
                              - od[(ef * 16 + 4 * lg + r) * 16 + lc] * i1;
                comb[ef][r] = o;
                ms += o * o;
            }
        ms += __shfl_xor(ms, 16);
        ms += __shfl_xor(ms, 32);
        const float sc = rsqrtf(ms * (1.f / 64.f) + 1e-5f) * 0.8f;
        const int nq = q0row + lc;
        if (nq < SEQ) {
            bf16_t* dst = &outp[(mb + nq) * DMODEL + h * EDIM + 4 * lg];
#pragma unroll
            for (int ef = 0; ef < 4; ++ef) {
                const f32x4 g4 = *(const f32x4*)&subg[ef * 16 + 4 * lg];
                const unsigned u0 = cvt_pk_bf16(comb[ef][0] * sc * g4[0],
                                                comb[ef][1] * sc * g4[1]);
                const unsigned u1 = cvt_pk_bf16(comb[ef][2] * sc * g4[2],
                                                comb[ef][3] * sc * g4[3]);
                *(uintx2*)(dst + ef * 16) = uintx2{u0, u1};
            }
        }
    }
}

// ---------------- launch ----------------
extern "C" void kernel_launch(void* const* d_in, const int* in_sizes, int n_in,
                              void* d_out, int out_size, void* d_ws, size_t ws_size,
                              hipStream_t stream)
{
    const float* x    = (const float*)d_in[0];
    const float* ln1g = (const float*)d_in[1];
    const float* ln1b = (const float*)d_in[2];
    const float* wq   = (const float*)d_in[3];
    const float* wk   = (const float*)d_in[4];
    const float* wv   = (const float*)d_in[5];
    const float* wo   = (const float*)d_in[6];
    const float* lq1  = (const float*)d_in[7];
    const float* lk1  = (const float*)d_in[8];
    const float* lq2  = (const float*)d_in[9];
    const float* lk2  = (const float*)d_in[10];
    const float* subg = (const float*)d_in[11];
    const float* ln2g = (const float*)d_in[12];
    const float* ln2b = (const float*)d_in[13];
    const float* w1   = (const float*)d_in[14];
    const float* b1   = (const float*)d_in[15];
    const float* w2   = (const float*)d_in[16];
    const float* b2   = (const float*)d_in[17];

    char* ws = (char*)d_ws;
    bf16_t* wAll = (bf16_t*)ws;               // wq|wk|wv (fused) | wo | w1 | w2
    bf16_t* wob = wAll + 1769472;
    bf16_t* w1b = wAll + 2359296;
    bf16_t* w2b = wAll + 4718592;
    ws += 7077888ull * 2;
    float* lamP = (float*)ws; ws += 256;
    bf16_t* xn   = (bf16_t*)ws; ws += (size_t)MPAD * DMODEL * 2;
    bf16_t* qkvb = (bf16_t*)ws;               // [MPAD][2304]; h1 aliases here later
    bf16_t* h1   = qkvb;
    ws += (size_t)MPAD * QKVSTR * 2;
    bf16_t* vtb  = (bf16_t*)ws; ws += (size_t)(BATCH * NH) * EDIM * NPAD * 2;
    bf16_t* aout = (bf16_t*)ws; ws += (size_t)MPAD * DMODEL * 2;
    float* x1    = (float*)ws;  ws += (size_t)MPAD * DMODEL * 4;

    wconv_kernel<<<6912, 256, 0, stream>>>(wq, wk, wv, wo, w1, w2, wAll);
    lam_kernel<<<1, 64, 0, stream>>>(lq1, lk1, lq2, lk2, lamP);
    ln_kernel<<<MPAD, 256, 0, stream>>>(x, ln1g, ln1b, xn, MROWS);

    // fused QKV: [MPAD][768] x [2304][768]^T
    gemm4<0><<<dim3(146, 9), 512, 0, stream>>>(xn, wAll, 768, QKVSTR, 24,
                                               qkvb, nullptr, nullptr, nullptr, MROWS);

    vtrans_kernel<<<dim3(10, 12, 32), 256, 0, stream>>>(qkvb, vtb);
    attn_kernel<<<dim3(10, 12, 32), 512, 0, stream>>>(qkvb, vtb, lamP, subg, aout);

    gemm4<1><<<dim3(146, 3), 512, 0, stream>>>(aout, wob, 768, 768, 24,
                                               nullptr, x1, nullptr, x, MROWS);
    ln_kernel<<<MPAD, 256, 0, stream>>>(x1, ln2g, ln2b, xn, MROWS);
    gemm4<2><<<dim3(146, 12), 512, 0, stream>>>(xn, w1b, 768, MLPD, 24,
                                                h1, nullptr, b1, nullptr, MROWS);
    gemm4<3><<<dim3(146, 3), 512, 0, stream>>>(h1, w2b, MLPD, 768, 96,
                                               nullptr, (float*)d_out, b2, x1, MROWS);
}